// Round 2
// baseline (890.851 us; speedup 1.0000x reference)
//
#include <hip/hip_runtime.h>

#define N_NODES 50000
#define N_EDGES 800000
#define N_EL    200000
#define CH      128

// ---------------- degree histogram (src-degree for norm, dst-count for CSR) --
__global__ void hist_kernel(const int* __restrict__ ei, int* deg, int* cnt){
  int i = blockIdx.x*blockDim.x + threadIdx.x;
  if (i < N_EDGES){
    int s = ei[i];
    int d = ei[N_EDGES + i];
    atomicAdd(&deg[s], 1);
    atomicAdd(&cnt[d], 1);
  }
}

__global__ void dinv_kernel(const int* __restrict__ deg, float* __restrict__ dinv){
  int i = blockIdx.x*blockDim.x + threadIdx.x;
  if (i < N_NODES){
    int d = deg[i];
    dinv[i] = d > 0 ? rsqrtf((float)d) : 0.0f;
  }
}

// ---------------- single-block exclusive scan over cnt -> rowoff, cursor -----
__global__ void scan_kernel(const int* __restrict__ cnt, int* __restrict__ rowoff,
                            int* __restrict__ cursor){
  __shared__ int sh[1024];
  __shared__ int carry;
  if (threadIdx.x == 0) carry = 0;
  __syncthreads();
  for (int base = 0; base < N_NODES; base += 1024){
    int i = base + (int)threadIdx.x;
    int v = (i < N_NODES) ? cnt[i] : 0;
    sh[threadIdx.x] = v;
    __syncthreads();
    for (int off = 1; off < 1024; off <<= 1){
      int t = (threadIdx.x >= off) ? sh[threadIdx.x - off] : 0;
      __syncthreads();
      sh[threadIdx.x] += t;
      __syncthreads();
    }
    int excl = sh[threadIdx.x] - v;
    if (i < N_NODES){ int o = carry + excl; rowoff[i] = o; cursor[i] = o; }
    __syncthreads();
    if (threadIdx.x == 0) carry += sh[1023];
    __syncthreads();
  }
  if (threadIdx.x == 0) rowoff[N_NODES] = carry;
}

__global__ void scatter_kernel(const int* __restrict__ ei, const float* __restrict__ dinv,
                               int* cursor, int* __restrict__ csr_src,
                               float* __restrict__ csr_norm){
  int i = blockIdx.x*blockDim.x + threadIdx.x;
  if (i < N_EDGES){
    int s = ei[i];
    int d = ei[N_EDGES + i];
    int pos = atomicAdd(&cursor[d], 1);
    csr_src[pos]  = s;
    csr_norm[pos] = -(dinv[s] * dinv[d]);
  }
}

// ---------------- prop: one wave per node, gather incoming edges -------------
template<int NMAT>
__global__ void prop_kernel(const int* __restrict__ rowoff, const int* __restrict__ csr_src,
                            const float* __restrict__ csr_norm,
                            const float* __restrict__ V0, const float* __restrict__ V1,
                            float* __restrict__ O0, float* __restrict__ O1){
  int node = blockIdx.x*4 + ((int)threadIdx.x >> 6);
  if (node >= N_NODES) return;
  int lane = threadIdx.x & 63;
  int beg = rowoff[node], end = rowoff[node+1];
  float2 a0 = make_float2(0.f, 0.f), a1 = make_float2(0.f, 0.f);
  for (int k = beg; k < end; ++k){
    int s = csr_src[k];
    float w = csr_norm[k];
    float2 v = *(const float2*)(V0 + (size_t)s*CH + lane*2);
    a0.x += w*v.x; a0.y += w*v.y;
    if (NMAT == 2){
      float2 u = *(const float2*)(V1 + (size_t)s*CH + lane*2);
      a1.x += w*u.x; a1.y += w*u.y;
    }
  }
  *(float2*)(O0 + (size_t)node*CH + lane*2) = a0;
  if (NMAT == 2) *(float2*)(O1 + (size_t)node*CH + lane*2) = a1;
}

// ---------------- K-stacked tile GEMM with fused gate epilogues --------------
// A blocks: up to 4 [N,128] matrices stacked in K. B blocks: [128,128] each.
// EPI: 0 Z=sigmoid   1 HR=H*sigmoid   2 raw (pre2)   3 final h/tanh/relu
template<int KT, int EPI>
__launch_bounds__(256)
__global__ void cheb_gemm(const float* __restrict__ A0, const float* __restrict__ A1,
                          const float* __restrict__ A2, const float* __restrict__ A3,
                          const float* __restrict__ B0, const float* __restrict__ B1,
                          const float* __restrict__ B2, const float* __restrict__ B3,
                          const float* __restrict__ bias0, const float* __restrict__ bias1,
                          const float* __restrict__ Hp, const float* __restrict__ pre2,
                          const float* __restrict__ Zp,
                          float* __restrict__ out0, float* __restrict__ out1){
  __shared__ float Asm[32][68];   // [kk][row], padded
  __shared__ float Bsm[32][132];  // [kk][col], padded
  const float* Ablk[4] = {A0, A1, A2, A3};
  const float* Bblk[4] = {B0, B1, B2, B3};
  int t = threadIdx.x;
  int r0tile = blockIdx.x * 64;
  int tx = t & 31, ty = t >> 5;
  int c0 = tx * 4;
  int rr = ty * 8;
  float acc[8][4];
  #pragma unroll
  for (int i = 0; i < 8; ++i)
    #pragma unroll
    for (int j = 0; j < 4; ++j) acc[i][j] = 0.f;

  for (int kt = 0; kt < KT; ++kt){
    const float* Ap = Ablk[kt >> 2] + (kt & 3) * 32;
    const float* Bp = Bblk[kt >> 2] + (kt & 3) * 32 * CH;
    #pragma unroll
    for (int p = 0; p < 2; ++p){           // A tile 64x32, store transposed
      int f = t + p*256;
      int r = f >> 3, cg = f & 7;
      int row = r0tile + r;
      float4 v = make_float4(0.f,0.f,0.f,0.f);
      if (row < N_NODES) v = *(const float4*)(Ap + (size_t)row*CH + cg*4);
      Asm[cg*4+0][r] = v.x; Asm[cg*4+1][r] = v.y;
      Asm[cg*4+2][r] = v.z; Asm[cg*4+3][r] = v.w;
    }
    #pragma unroll
    for (int p = 0; p < 4; ++p){           // B tile 32x128
      int f = t + p*256;
      int kk = f >> 5, cg = f & 31;
      *(float4*)&Bsm[kk][cg*4] = *(const float4*)(Bp + kk*CH + cg*4);
    }
    __syncthreads();
    #pragma unroll
    for (int kk = 0; kk < 32; ++kk){
      float4 b  = *(float4*)&Bsm[kk][c0];
      float4 a0v = *(float4*)&Asm[kk][rr];
      float4 a1v = *(float4*)&Asm[kk][rr+4];
      float a[8] = {a0v.x,a0v.y,a0v.z,a0v.w,a1v.x,a1v.y,a1v.z,a1v.w};
      #pragma unroll
      for (int i = 0; i < 8; ++i){
        acc[i][0] += a[i]*b.x; acc[i][1] += a[i]*b.y;
        acc[i][2] += a[i]*b.z; acc[i][3] += a[i]*b.w;
      }
    }
    __syncthreads();
  }

  float bsum[4];
  #pragma unroll
  for (int j = 0; j < 4; ++j)
    bsum[j] = bias0[c0+j] + (bias1 ? bias1[c0+j] : 0.f);

  #pragma unroll
  for (int i = 0; i < 8; ++i){
    int row = r0tile + rr + i;
    if (row >= N_NODES) break;
    size_t o = (size_t)row*CH + c0;
    float4 res;
    float* rp = &res.x;
    #pragma unroll
    for (int j = 0; j < 4; ++j){
      float v = acc[i][j] + bsum[j];
      if (EPI == 0){
        rp[j] = 1.0f/(1.0f + __expf(-v));
      } else if (EPI == 1){
        float rg = 1.0f/(1.0f + __expf(-v));
        rp[j] = Hp[o+j] * rg;
      } else if (EPI == 2){
        rp[j] = v;
      } else {
        float ht = tanhf(v + pre2[o+j]);
        float z  = Zp[o+j];
        float h  = z*Hp[o+j] + (1.0f - z)*ht;
        rp[j] = h;
        out1[o+j] = fmaxf(h, 0.0f);
      }
    }
    *(float4*)(out0 + o) = res;
  }
}

// ---------------- link-pred scores: one 32-lane group per pair ---------------
__global__ void scores_kernel(const int* __restrict__ eli, const float* __restrict__ hr,
                              const float* __restrict__ pw, const float* __restrict__ pb,
                              float* __restrict__ out){
  int pair = blockIdx.x*8 + ((int)threadIdx.x >> 5);
  if (pair >= N_EL) return;
  int lane = threadIdx.x & 31;
  int a = eli[pair];
  int b = eli[N_EL + pair];
  float4 va = *(const float4*)(hr + (size_t)a*CH + lane*4);
  float4 vb = *(const float4*)(hr + (size_t)b*CH + lane*4);
  int k0 = lane*4;
  float w0 = pw[(k0+0)*2] + pw[(k0+0)*2+1];
  float w1 = pw[(k0+1)*2] + pw[(k0+1)*2+1];
  float w2 = pw[(k0+2)*2] + pw[(k0+2)*2+1];
  float w3 = pw[(k0+3)*2] + pw[(k0+3)*2+1];
  float s = va.x*vb.x*w0 + va.y*vb.y*w1 + va.z*vb.z*w2 + va.w*vb.w*w3;
  #pragma unroll
  for (int off = 16; off >= 1; off >>= 1) s += __shfl_xor(s, off, 64);
  if (lane == 0) out[pair] = s + pb[0] + pb[1];
}

extern "C" void kernel_launch(void* const* d_in, const int* in_sizes, int n_in,
                              void* d_out, int out_size, void* d_ws, size_t ws_size,
                              hipStream_t stream) {
  const float* x   = (const float*)d_in[0];
  const int*   ei  = (const int*)d_in[1];
  const int*   eli = (const int*)d_in[2];
  const float* H   = (const float*)d_in[3];
  const float* Wx0 = (const float*)d_in[4];
  const float* Wx1 = (const float*)d_in[5];
  const float* bx  = (const float*)d_in[6];
  const float* Wh0 = (const float*)d_in[7];
  const float* Wh1 = (const float*)d_in[8];
  const float* bh  = (const float*)d_in[9];
  const float* pw  = (const float*)d_in[10];
  const float* pb  = (const float*)d_in[11];
  float* out    = (float*)d_out;
  float* scores = out;
  float* hidden = out + N_EL;

  // Workspace layout (total ~110 MB; pre2 aliases pH, relu(h) aliases HRb)
  char* w = (char*)d_ws;
  auto alloc = [&](size_t b){ void* p = (void*)w; w += (b + 255) & ~(size_t)255; return p; };
  int*   deg      = (int*)  alloc((size_t)N_NODES*4);
  int*   cnt      = (int*)  alloc((size_t)N_NODES*4);
  float* dinv     = (float*)alloc((size_t)N_NODES*4);
  int*   rowoff   = (int*)  alloc((size_t)(N_NODES+1)*4);
  int*   cursor   = (int*)  alloc((size_t)N_NODES*4);
  int*   csr_src  = (int*)  alloc((size_t)N_EDGES*4);
  float* csr_norm = (float*)alloc((size_t)N_EDGES*4);
  float* px   = (float*)alloc((size_t)N_NODES*CH*4);
  float* pH   = (float*)alloc((size_t)N_NODES*CH*4);
  float* Zb   = (float*)alloc((size_t)N_NODES*CH*4);
  float* HRb  = (float*)alloc((size_t)N_NODES*CH*4);
  float* pre2 = pH;    // pH is dead after gates 0/1 consume it
  float* relu = HRb;   // final gemm reads only its own A-rows before writing

  hipMemsetAsync(deg, 0, (size_t)N_NODES*4, stream);
  hipMemsetAsync(cnt, 0, (size_t)N_NODES*4, stream);

  hist_kernel<<<(N_EDGES+255)/256, 256, 0, stream>>>(ei, deg, cnt);
  dinv_kernel<<<(N_NODES+255)/256, 256, 0, stream>>>(deg, dinv);
  scan_kernel<<<1, 1024, 0, stream>>>(cnt, rowoff, cursor);
  scatter_kernel<<<(N_EDGES+255)/256, 256, 0, stream>>>(ei, dinv, cursor, csr_src, csr_norm);

  prop_kernel<2><<<(N_NODES+3)/4, 256, 0, stream>>>(rowoff, csr_src, csr_norm, x, H, px, pH);

  const int GB = (N_NODES + 63) / 64;
  // gate 0: Z
  cheb_gemm<16,0><<<GB, 256, 0, stream>>>(x, px, H, pH,
      Wx0, Wx1, Wh0, Wh1, bx, bh,
      nullptr, nullptr, nullptr, Zb, nullptr);
  // gate 1: HR = H * sigmoid(...)
  cheb_gemm<16,1><<<GB, 256, 0, stream>>>(x, px, H, pH,
      Wx0+16384, Wx1+16384, Wh0+16384, Wh1+16384, bx+128, bh+128,
      H, nullptr, nullptr, HRb, nullptr);
  // gate 2 x-part: pre2 = x@Wx0[2] + px@Wx1[2] + bx[2]   (pre2 aliases pH — pH dead now)
  cheb_gemm<8,2><<<GB, 256, 0, stream>>>(x, px, nullptr, nullptr,
      Wx0+32768, Wx1+32768, nullptr, nullptr, bx+256, nullptr,
      nullptr, nullptr, nullptr, pre2, nullptr);

  // pHR = prop(HR)  (reuse px buffer)
  prop_kernel<1><<<(N_NODES+3)/4, 256, 0, stream>>>(rowoff, csr_src, csr_norm, HRb, nullptr, px, nullptr);

  // gate 2 h-part + GRU finalize: hidden (d_out) + relu(h) (in-place into HRb)
  cheb_gemm<8,3><<<GB, 256, 0, stream>>>(HRb, px, nullptr, nullptr,
      Wh0+32768, Wh1+32768, nullptr, nullptr, bh+256, nullptr,
      H, pre2, Zb, hidden, relu);

  scores_kernel<<<(N_EL+7)/8, 256, 0, stream>>>(eli, relu, pw, pb, scores);
}

// Round 3
// 605.855 us; speedup vs baseline: 1.4704x; 1.4704x over previous
//
#include <hip/hip_runtime.h>

#define N_NODES 50000
#define N_EDGES 800000
#define N_EL    200000
#define CH      128

typedef __attribute__((ext_vector_type(8))) short bf16x8;
typedef __attribute__((ext_vector_type(4))) float f32x4;

__device__ __forceinline__ unsigned short f2bf(float f){
  unsigned int u = __float_as_uint(f);
  unsigned int r = (u + 0x7fff + ((u >> 16) & 1)) >> 16;
  return (unsigned short)r;
}
__device__ __forceinline__ float bflo(unsigned int v){ return __uint_as_float(v << 16); }
__device__ __forceinline__ float bfhi(unsigned int v){ return __uint_as_float(v & 0xffff0000u); }

// ---------------- degree histogram --------------------------------------------
__global__ void hist_kernel(const int* __restrict__ ei, int* deg, int* cnt){
  int i = blockIdx.x*blockDim.x + threadIdx.x;
  if (i < N_EDGES){
    atomicAdd(&deg[ei[i]], 1);
    atomicAdd(&cnt[ei[N_EDGES + i]], 1);
  }
}

__global__ void dinv_kernel(const int* __restrict__ deg, float* __restrict__ dinv){
  int i = blockIdx.x*blockDim.x + threadIdx.x;
  if (i < N_NODES){
    int d = deg[i];
    dinv[i] = d > 0 ? rsqrtf((float)d) : 0.0f;
  }
}

// ---------------- hierarchical exclusive scan (3 kernels) ---------------------
#define SCAN_NB 196   // ceil(50000/256)

__global__ void scan_bsum(const int* __restrict__ cnt, int* __restrict__ bsum){
  __shared__ int sh[256];
  int i = blockIdx.x*256 + threadIdx.x;
  sh[threadIdx.x] = (i < N_NODES) ? cnt[i] : 0;
  __syncthreads();
  for (int off = 128; off >= 1; off >>= 1){
    if ((int)threadIdx.x < off) sh[threadIdx.x] += sh[threadIdx.x + off];
    __syncthreads();
  }
  if (threadIdx.x == 0) bsum[blockIdx.x] = sh[0];
}

__global__ void scan_boff(const int* __restrict__ bsum, int* __restrict__ boff){
  __shared__ int sh[256];
  int t = threadIdx.x;
  int v = (t < SCAN_NB) ? bsum[t] : 0;
  sh[t] = v;
  __syncthreads();
  for (int off = 1; off < 256; off <<= 1){
    int tv = (t >= off) ? sh[t - off] : 0;
    __syncthreads();
    sh[t] += tv;
    __syncthreads();
  }
  if (t < SCAN_NB) boff[t] = sh[t] - v;
}

__global__ void scan_final(const int* __restrict__ cnt, const int* __restrict__ boff,
                           int* __restrict__ rowoff, int* __restrict__ cursor){
  __shared__ int sh[256];
  int t = threadIdx.x;
  int i = blockIdx.x*256 + t;
  int v = (i < N_NODES) ? cnt[i] : 0;
  sh[t] = v;
  __syncthreads();
  for (int off = 1; off < 256; off <<= 1){
    int tv = (t >= off) ? sh[t - off] : 0;
    __syncthreads();
    sh[t] += tv;
    __syncthreads();
  }
  int o = boff[blockIdx.x] + sh[t] - v;
  if (i < N_NODES){ rowoff[i] = o; cursor[i] = o; }
  if (i == N_NODES - 1) rowoff[N_NODES] = N_EDGES;
}

__global__ void scatter_kernel(const int* __restrict__ ei, const float* __restrict__ dinv,
                               int* cursor, int* __restrict__ csr_src,
                               float* __restrict__ csr_norm){
  int i = blockIdx.x*blockDim.x + threadIdx.x;
  if (i < N_EDGES){
    int s = ei[i];
    int d = ei[N_EDGES + i];
    int pos = atomicAdd(&cursor[d], 1);
    csr_src[pos]  = s;
    csr_norm[pos] = -(dinv[s] * dinv[d]);
  }
}

// ---------------- converts ----------------------------------------------------
__global__ void cvt_xH(const float* __restrict__ x, const float* __restrict__ H,
                       unsigned short* __restrict__ xb, unsigned short* __restrict__ Hb){
  const int Q = (N_NODES*CH)/4;  // float4 groups per array
  int i = blockIdx.x*blockDim.x + threadIdx.x;
  if (i >= 2*Q) return;
  const float* src; unsigned short* dst; int off;
  if (i < Q){ src = x; dst = xb; off = i; } else { src = H; dst = Hb; off = i - Q; }
  float4 v = ((const float4*)src)[off];
  uint2 o;
  o.x = (unsigned int)f2bf(v.x) | ((unsigned int)f2bf(v.y) << 16);
  o.y = (unsigned int)f2bf(v.z) | ((unsigned int)f2bf(v.w) << 16);
  ((uint2*)dst)[off] = o;
}

// wt[m][col][k] = W_t[g][k][col], m = t*3+g, t in {Wx0,Wx1,Wh0,Wh1}
__global__ void cvt_w(const float* __restrict__ Wx0, const float* __restrict__ Wx1,
                      const float* __restrict__ Wh0, const float* __restrict__ Wh1,
                      unsigned short* __restrict__ wt){
  int i = blockIdx.x*blockDim.x + threadIdx.x;
  if (i >= 12*128*128) return;
  int m = i >> 14;
  int r = i & 16383;
  int col = r >> 7, k = r & 127;
  const float* W[4] = {Wx0, Wx1, Wh0, Wh1};
  const float* src = W[m/3] + (m%3)*16384;
  wt[i] = f2bf(src[k*128 + col]);
}

// ---------------- prop (bf16 in/out, fp32 accumulate) -------------------------
template<int NMAT>
__global__ void prop_bf16(const int* __restrict__ rowoff, const int* __restrict__ csr_src,
                          const float* __restrict__ csr_norm,
                          const unsigned short* __restrict__ V0,
                          const unsigned short* __restrict__ V1,
                          unsigned short* __restrict__ O0, unsigned short* __restrict__ O1){
  int node = blockIdx.x*4 + ((int)threadIdx.x >> 6);
  if (node >= N_NODES) return;
  int lane = threadIdx.x & 63;
  int beg = rowoff[node], end = rowoff[node+1];
  float a0 = 0.f, a1 = 0.f, b0 = 0.f, b1 = 0.f;
  for (int k = beg; k < end; ++k){
    int s = csr_src[k];
    float w = csr_norm[k];
    unsigned int v = *(const unsigned int*)(V0 + (size_t)s*CH + lane*2);
    a0 += w * bflo(v); a1 += w * bfhi(v);
    if (NMAT == 2){
      unsigned int u = *(const unsigned int*)(V1 + (size_t)s*CH + lane*2);
      b0 += w * bflo(u); b1 += w * bfhi(u);
    }
  }
  unsigned int o0 = (unsigned int)f2bf(a0) | ((unsigned int)f2bf(a1) << 16);
  *(unsigned int*)(O0 + (size_t)node*CH + lane*2) = o0;
  if (NMAT == 2){
    unsigned int o1 = (unsigned int)f2bf(b0) | ((unsigned int)f2bf(b1) << 16);
    *(unsigned int*)(O1 + (size_t)node*CH + lane*2) = o1;
  }
}

// ---------------- MFMA gate GEMM (bf16 in, fp32 acc, fused epilogues) ---------
// Block: 256 thr = 4 waves, 128 rows; wave w owns rows [bid*128+w*32, +32).
// A: NMAT bf16 [N][128] matrices (K-stacked). B: NMAT bf16 B^T [128col][128k].
// EPI: 0 Z=sigmoid->f32  1 HR=H*sigmoid->bf16  2 raw->f32  3 final GRU
template<int NMAT, int EPI>
__launch_bounds__(256)
__global__ void mfma_gemm(const unsigned short* __restrict__ A0, const unsigned short* __restrict__ A1,
                          const unsigned short* __restrict__ A2, const unsigned short* __restrict__ A3,
                          const unsigned short* __restrict__ B0, const unsigned short* __restrict__ B1,
                          const unsigned short* __restrict__ B2, const unsigned short* __restrict__ B3,
                          const float* __restrict__ bias0, const float* __restrict__ bias1,
                          const float* __restrict__ Hp, const float* pre2,
                          const float* __restrict__ Zp,
                          float* __restrict__ out0, float* out1f,
                          unsigned short* __restrict__ out1b){
  const unsigned short* Am[4] = {A0, A1, A2, A3};
  const unsigned short* Bm[4] = {B0, B1, B2, B3};
  int lane = threadIdx.x & 63;
  int w    = threadIdx.x >> 6;
  int lr = lane & 15;          // row-in-A-frag / col-in-B-frag
  int kb = (lane >> 4) * 8;    // k offset within 32
  int r0 = blockIdx.x * 128 + w * 32;

  f32x4 acc[2][8];
  #pragma unroll
  for (int i = 0; i < 2; ++i)
    #pragma unroll
    for (int c = 0; c < 8; ++c) acc[i][c] = (f32x4){0.f,0.f,0.f,0.f};

  int rA0 = min(r0 + lr,      N_NODES - 1);
  int rA1 = min(r0 + 16 + lr, N_NODES - 1);

  #pragma unroll
  for (int s = 0; s < NMAT*4; ++s){
    const unsigned short* Ap = Am[s >> 2] + (s & 3)*32 + kb;
    const unsigned short* Bp = Bm[s >> 2] + (s & 3)*32 + kb;
    bf16x8 a0 = *(const bf16x8*)(Ap + (size_t)rA0*CH);
    bf16x8 a1 = *(const bf16x8*)(Ap + (size_t)rA1*CH);
    #pragma unroll
    for (int c = 0; c < 8; ++c){
      bf16x8 b = *(const bf16x8*)(Bp + (size_t)(c*16 + lr)*CH);
      acc[0][c] = __builtin_amdgcn_mfma_f32_16x16x32_bf16(a0, b, acc[0][c], 0, 0, 0);
      acc[1][c] = __builtin_amdgcn_mfma_f32_16x16x32_bf16(a1, b, acc[1][c], 0, 0, 0);
    }
  }

  float bs[8];
  #pragma unroll
  for (int c = 0; c < 8; ++c)
    bs[c] = bias0[c*16 + lr] + (bias1 ? bias1[c*16 + lr] : 0.f);

  int rbase = r0 + (lane >> 4) * 4;
  #pragma unroll
  for (int i = 0; i < 2; ++i){
    #pragma unroll
    for (int j = 0; j < 4; ++j){
      int row = rbase + i*16 + j;
      if (row >= N_NODES) continue;
      size_t ro = (size_t)row * CH;
      #pragma unroll
      for (int c = 0; c < 8; ++c){
        int col = c*16 + lr;
        size_t o = ro + col;
        float v = acc[i][c][j] + bs[c];
        if (EPI == 0){
          out0[o] = 1.0f/(1.0f + __expf(-v));
        } else if (EPI == 1){
          float rg = 1.0f/(1.0f + __expf(-v));
          out1b[o] = f2bf(Hp[o] * rg);
        } else if (EPI == 2){
          out0[o] = v;
        } else {
          float ht = tanhf(v + pre2[o]);
          float z  = Zp[o];
          float h  = z*Hp[o] + (1.0f - z)*ht;
          out0[o]  = h;
          out1f[o] = fmaxf(h, 0.0f);
        }
      }
    }
  }
}

// ---------------- link-pred scores -------------------------------------------
__global__ void scores_kernel(const int* __restrict__ eli, const float* __restrict__ hr,
                              const float* __restrict__ pw, const float* __restrict__ pb,
                              float* __restrict__ out){
  int pair = blockIdx.x*8 + ((int)threadIdx.x >> 5);
  if (pair >= N_EL) return;
  int lane = threadIdx.x & 31;
  int a = eli[pair];
  int b = eli[N_EL + pair];
  float4 va = *(const float4*)(hr + (size_t)a*CH + lane*4);
  float4 vb = *(const float4*)(hr + (size_t)b*CH + lane*4);
  int k0 = lane*4;
  float w0 = pw[(k0+0)*2] + pw[(k0+0)*2+1];
  float w1 = pw[(k0+1)*2] + pw[(k0+1)*2+1];
  float w2 = pw[(k0+2)*2] + pw[(k0+2)*2+1];
  float w3 = pw[(k0+3)*2] + pw[(k0+3)*2+1];
  float s = va.x*vb.x*w0 + va.y*vb.y*w1 + va.z*vb.z*w2 + va.w*vb.w*w3;
  #pragma unroll
  for (int off = 16; off >= 1; off >>= 1) s += __shfl_xor(s, off, 64);
  if (lane == 0) out[pair] = s + pb[0] + pb[1];
}

extern "C" void kernel_launch(void* const* d_in, const int* in_sizes, int n_in,
                              void* d_out, int out_size, void* d_ws, size_t ws_size,
                              hipStream_t stream) {
  const float* x   = (const float*)d_in[0];
  const int*   ei  = (const int*)d_in[1];
  const int*   eli = (const int*)d_in[2];
  const float* H   = (const float*)d_in[3];
  const float* Wx0 = (const float*)d_in[4];
  const float* Wx1 = (const float*)d_in[5];
  const float* bx  = (const float*)d_in[6];
  const float* Wh0 = (const float*)d_in[7];
  const float* Wh1 = (const float*)d_in[8];
  const float* bh  = (const float*)d_in[9];
  const float* pw  = (const float*)d_in[10];
  const float* pb  = (const float*)d_in[11];
  float* out    = (float*)d_out;
  float* scores = out;
  float* hidden = out + N_EL;

  // Workspace (~110 MB). Aliases: HRb_b -> Hb (row-safe), pHRb -> pHb, relu -> pre2.
  char* w = (char*)d_ws;
  auto alloc = [&](size_t b){ void* p = (void*)w; w += (b + 255) & ~(size_t)255; return p; };
  int*   deg      = (int*)  alloc((size_t)N_NODES*4);
  int*   cnt      = (int*)  alloc((size_t)N_NODES*4);
  float* dinv     = (float*)alloc((size_t)N_NODES*4);
  int*   rowoff   = (int*)  alloc((size_t)(N_NODES+1)*4);
  int*   cursor   = (int*)  alloc((size_t)N_NODES*4);
  int*   bsum     = (int*)  alloc((size_t)SCAN_NB*4);
  int*   boff     = (int*)  alloc((size_t)SCAN_NB*4);
  int*   csr_src  = (int*)  alloc((size_t)N_EDGES*4);
  float* csr_norm = (float*)alloc((size_t)N_EDGES*4);
  unsigned short* wt  = (unsigned short*)alloc((size_t)12*128*128*2);
  unsigned short* xb  = (unsigned short*)alloc((size_t)N_NODES*CH*2);
  unsigned short* Hb  = (unsigned short*)alloc((size_t)N_NODES*CH*2);
  unsigned short* pxb = (unsigned short*)alloc((size_t)N_NODES*CH*2);
  unsigned short* pHb = (unsigned short*)alloc((size_t)N_NODES*CH*2);
  float* Zb   = (float*)alloc((size_t)N_NODES*CH*4);
  float* pre2 = (float*)alloc((size_t)N_NODES*CH*4);
  unsigned short* HRb_b = Hb;    // gemm1 writes its own rows after reading them
  unsigned short* pHRb  = pHb;   // prop<1> reads Hb, writes pHb space
  float* relu = pre2;            // EPI=3: per-element read pre2 then write relu

  hipMemsetAsync(deg, 0, (size_t)N_NODES*4, stream);
  hipMemsetAsync(cnt, 0, (size_t)N_NODES*4, stream);

  hist_kernel<<<(N_EDGES+255)/256, 256, 0, stream>>>(ei, deg, cnt);
  dinv_kernel<<<(N_NODES+255)/256, 256, 0, stream>>>(deg, dinv);
  scan_bsum <<<SCAN_NB, 256, 0, stream>>>(cnt, bsum);
  scan_boff <<<1, 256, 0, stream>>>(bsum, boff);
  scan_final<<<SCAN_NB, 256, 0, stream>>>(cnt, boff, rowoff, cursor);
  scatter_kernel<<<(N_EDGES+255)/256, 256, 0, stream>>>(ei, dinv, cursor, csr_src, csr_norm);

  cvt_xH<<<( (N_NODES*CH/4)*2 + 255)/256, 256, 0, stream>>>(x, H, xb, Hb);
  cvt_w <<<(12*128*128 + 255)/256, 256, 0, stream>>>(Wx0, Wx1, Wh0, Wh1, wt);

  prop_bf16<2><<<(N_NODES+3)/4, 256, 0, stream>>>(rowoff, csr_src, csr_norm, xb, Hb, pxb, pHb);

  const int GB = (N_NODES + 127) / 128;
  const int M = 128*128;
  // gate 0: Z (fp32)
  mfma_gemm<4,0><<<GB, 256, 0, stream>>>(xb, pxb, Hb, pHb,
      wt + 0*M, wt + 3*M, wt + 6*M, wt + 9*M,
      bx, bh, nullptr, nullptr, nullptr, Zb, nullptr, nullptr);
  // gate 1: HR = H * sigmoid(...) (bf16, in-place over Hb)
  mfma_gemm<4,1><<<GB, 256, 0, stream>>>(xb, pxb, Hb, pHb,
      wt + 1*M, wt + 4*M, wt + 7*M, wt + 10*M,
      bx + 128, bh + 128, H, nullptr, nullptr, nullptr, nullptr, HRb_b);
  // gate 2 x-part: pre2 (fp32)
  mfma_gemm<2,2><<<GB, 256, 0, stream>>>(xb, pxb, nullptr, nullptr,
      wt + 2*M, wt + 5*M, nullptr, nullptr,
      bx + 256, nullptr, nullptr, nullptr, nullptr, pre2, nullptr, nullptr);

  // pHR = prop(HR)
  prop_bf16<1><<<(N_NODES+3)/4, 256, 0, stream>>>(rowoff, csr_src, csr_norm, HRb_b, nullptr, pHRb, nullptr);

  // gate 2 h-part + GRU finalize: hidden (d_out) + relu (aliases pre2)
  mfma_gemm<2,3><<<GB, 256, 0, stream>>>(HRb_b, pHRb, nullptr, nullptr,
      wt + 8*M, wt + 11*M, nullptr, nullptr,
      bh + 256, nullptr, H, pre2, Zb, hidden, relu, nullptr);

  scores_kernel<<<(N_EL+7)/8, 256, 0, stream>>>(eli, relu, pw, pb, scores);
}

// Round 4
// 514.184 us; speedup vs baseline: 1.7326x; 1.1783x over previous
//
#include <hip/hip_runtime.h>

#define N_NODES 50000
#define N_EDGES 800000
#define N_EL    200000
#define CH      128

typedef __attribute__((ext_vector_type(8))) short bf16x8;
typedef __attribute__((ext_vector_type(4))) float f32x4;

__device__ __forceinline__ unsigned short f2bf(float f){
  unsigned int u = __float_as_uint(f);
  unsigned int r = (u + 0x7fff + ((u >> 16) & 1)) >> 16;
  return (unsigned short)r;
}
__device__ __forceinline__ float bflo(unsigned int v){ return __uint_as_float(v << 16); }
__device__ __forceinline__ float bfhi(unsigned int v){ return __uint_as_float(v & 0xffff0000u); }
__device__ __forceinline__ float bf2f(unsigned short u){ return __uint_as_float(((unsigned int)u) << 16); }

// ---------------- degree histogram --------------------------------------------
__global__ void hist_kernel(const int* __restrict__ ei, int* deg, int* cnt){
  int i = blockIdx.x*blockDim.x + threadIdx.x;
  if (i < N_EDGES){
    atomicAdd(&deg[ei[i]], 1);
    atomicAdd(&cnt[ei[N_EDGES + i]], 1);
  }
}

__global__ void dinv_kernel(const int* __restrict__ deg, float* __restrict__ dinv){
  int i = blockIdx.x*blockDim.x + threadIdx.x;
  if (i < N_NODES){
    int d = deg[i];
    dinv[i] = d > 0 ? rsqrtf((float)d) : 0.0f;
  }
}

// ---------------- hierarchical exclusive scan ---------------------------------
#define SCAN_NB 196   // ceil(50000/256)

__global__ void scan_bsum(const int* __restrict__ cnt, int* __restrict__ bsum){
  __shared__ int sh[256];
  int i = blockIdx.x*256 + threadIdx.x;
  sh[threadIdx.x] = (i < N_NODES) ? cnt[i] : 0;
  __syncthreads();
  for (int off = 128; off >= 1; off >>= 1){
    if ((int)threadIdx.x < off) sh[threadIdx.x] += sh[threadIdx.x + off];
    __syncthreads();
  }
  if (threadIdx.x == 0) bsum[blockIdx.x] = sh[0];
}

__global__ void scan_boff(const int* __restrict__ bsum, int* __restrict__ boff){
  __shared__ int sh[256];
  int t = threadIdx.x;
  int v = (t < SCAN_NB) ? bsum[t] : 0;
  sh[t] = v;
  __syncthreads();
  for (int off = 1; off < 256; off <<= 1){
    int tv = (t >= off) ? sh[t - off] : 0;
    __syncthreads();
    sh[t] += tv;
    __syncthreads();
  }
  if (t < SCAN_NB) boff[t] = sh[t] - v;
}

__global__ void scan_final(const int* __restrict__ cnt, const int* __restrict__ boff,
                           int* __restrict__ rowoff, int* __restrict__ cursor){
  __shared__ int sh[256];
  int t = threadIdx.x;
  int i = blockIdx.x*256 + t;
  int v = (i < N_NODES) ? cnt[i] : 0;
  sh[t] = v;
  __syncthreads();
  for (int off = 1; off < 256; off <<= 1){
    int tv = (t >= off) ? sh[t - off] : 0;
    __syncthreads();
    sh[t] += tv;
    __syncthreads();
  }
  int o = boff[blockIdx.x] + sh[t] - v;
  if (i < N_NODES){ rowoff[i] = o; cursor[i] = o; }
  if (i == N_NODES - 1) rowoff[N_NODES] = N_EDGES;
}

__global__ void scatter_kernel(const int* __restrict__ ei, const float* __restrict__ dinv,
                               int* cursor, int* __restrict__ csr_src,
                               float* __restrict__ csr_norm){
  int i = blockIdx.x*blockDim.x + threadIdx.x;
  if (i < N_EDGES){
    int s = ei[i];
    int d = ei[N_EDGES + i];
    int pos = atomicAdd(&cursor[d], 1);
    csr_src[pos]  = s;
    csr_norm[pos] = -(dinv[s] * dinv[d]);
  }
}

// ---------------- converts ----------------------------------------------------
// xH[node][0..127]=bf16(x row), [128..255]=bf16(H row)
__global__ void cvt_xH(const float* __restrict__ x, const float* __restrict__ H,
                       unsigned short* __restrict__ xH){
  const int Q = (N_NODES*CH)/4;  // float4 groups per array
  int i = blockIdx.x*blockDim.x + threadIdx.x;
  if (i >= 2*Q) return;
  const float* src = (i < Q) ? x : H;
  int off = (i < Q) ? i : i - Q;
  float4 v = ((const float4*)src)[off];
  int node = off >> 5, cg = off & 31;
  uint2 o;
  o.x = (unsigned int)f2bf(v.x) | ((unsigned int)f2bf(v.y) << 16);
  o.y = (unsigned int)f2bf(v.z) | ((unsigned int)f2bf(v.w) << 16);
  *(uint2*)(xH + (size_t)node*256 + ((i < Q) ? 0 : 128) + cg*4) = o;
}

// wt[m][col][k] = W_t[g][k][col], m = t*3+g, t in {Wx0,Wx1,Wh0,Wh1}
__global__ void cvt_w(const float* __restrict__ Wx0, const float* __restrict__ Wx1,
                      const float* __restrict__ Wh0, const float* __restrict__ Wh1,
                      unsigned short* __restrict__ wt){
  int i = blockIdx.x*blockDim.x + threadIdx.x;
  if (i >= 12*128*128) return;
  int m = i >> 14;
  int r = i & 16383;
  int col = r >> 7, k = r & 127;
  const float* W[4] = {Wx0, Wx1, Wh0, Wh1};
  const float* src = W[m/3] + (m%3)*16384;
  wt[i] = f2bf(src[k*128 + col]);
}

// ---------------- prop over interleaved x|H (one 512B read per edge) ----------
__global__ void prop_x2(const int* __restrict__ rowoff, const int* __restrict__ csr_src,
                        const float* __restrict__ csr_norm,
                        const unsigned short* __restrict__ xH,
                        unsigned short* __restrict__ px, unsigned short* __restrict__ pH){
  int node = blockIdx.x*4 + ((int)threadIdx.x >> 6);
  if (node >= N_NODES) return;
  int lane = threadIdx.x & 63;
  int half = lane >> 5, il = lane & 31;
  const unsigned short* base = xH + half*128 + il*4;
  int beg = rowoff[node], end = rowoff[node+1];
  float a0 = 0.f, a1 = 0.f, a2 = 0.f, a3 = 0.f;
  int k = beg;
  for (; k + 4 <= end; k += 4){
    int s0 = csr_src[k], s1 = csr_src[k+1], s2 = csr_src[k+2], s3 = csr_src[k+3];
    float w0 = csr_norm[k], w1 = csr_norm[k+1], w2 = csr_norm[k+2], w3 = csr_norm[k+3];
    uint2 v0 = *(const uint2*)(base + (size_t)s0*256);
    uint2 v1 = *(const uint2*)(base + (size_t)s1*256);
    uint2 v2 = *(const uint2*)(base + (size_t)s2*256);
    uint2 v3 = *(const uint2*)(base + (size_t)s3*256);
    a0 += w0*bflo(v0.x) + w1*bflo(v1.x) + w2*bflo(v2.x) + w3*bflo(v3.x);
    a1 += w0*bfhi(v0.x) + w1*bfhi(v1.x) + w2*bfhi(v2.x) + w3*bfhi(v3.x);
    a2 += w0*bflo(v0.y) + w1*bflo(v1.y) + w2*bflo(v2.y) + w3*bflo(v3.y);
    a3 += w0*bfhi(v0.y) + w1*bfhi(v1.y) + w2*bfhi(v2.y) + w3*bfhi(v3.y);
  }
  for (; k < end; ++k){
    int s = csr_src[k];
    float w = csr_norm[k];
    uint2 v = *(const uint2*)(base + (size_t)s*256);
    a0 += w*bflo(v.x); a1 += w*bfhi(v.x);
    a2 += w*bflo(v.y); a3 += w*bfhi(v.y);
  }
  uint2 o;
  o.x = (unsigned int)f2bf(a0) | ((unsigned int)f2bf(a1) << 16);
  o.y = (unsigned int)f2bf(a2) | ((unsigned int)f2bf(a3) << 16);
  unsigned short* O = (half ? pH : px) + (size_t)node*CH + il*4;
  *(uint2*)O = o;
}

// ---------------- prop of one matrix (stride-256 input, e.g. HR half) ---------
__global__ void prop_one(const int* __restrict__ rowoff, const int* __restrict__ csr_src,
                         const float* __restrict__ csr_norm,
                         const unsigned short* __restrict__ V, // stride 256
                         unsigned short* __restrict__ O){      // stride 128
  int node = blockIdx.x*4 + ((int)threadIdx.x >> 6);
  if (node >= N_NODES) return;
  int lane = threadIdx.x & 63;
  const unsigned short* base = V + lane*2;
  int beg = rowoff[node], end = rowoff[node+1];
  float a0 = 0.f, a1 = 0.f;
  int k = beg;
  for (; k + 4 <= end; k += 4){
    int s0 = csr_src[k], s1 = csr_src[k+1], s2 = csr_src[k+2], s3 = csr_src[k+3];
    float w0 = csr_norm[k], w1 = csr_norm[k+1], w2 = csr_norm[k+2], w3 = csr_norm[k+3];
    unsigned int v0 = *(const unsigned int*)(base + (size_t)s0*256);
    unsigned int v1 = *(const unsigned int*)(base + (size_t)s1*256);
    unsigned int v2 = *(const unsigned int*)(base + (size_t)s2*256);
    unsigned int v3 = *(const unsigned int*)(base + (size_t)s3*256);
    a0 += w0*bflo(v0) + w1*bflo(v1) + w2*bflo(v2) + w3*bflo(v3);
    a1 += w0*bfhi(v0) + w1*bfhi(v1) + w2*bfhi(v2) + w3*bfhi(v3);
  }
  for (; k < end; ++k){
    int s = csr_src[k];
    float w = csr_norm[k];
    unsigned int v = *(const unsigned int*)(base + (size_t)s*256);
    a0 += w*bflo(v); a1 += w*bfhi(v);
  }
  *(unsigned int*)(O + (size_t)node*CH + lane*2) =
      (unsigned int)f2bf(a0) | ((unsigned int)f2bf(a1) << 16);
}

// ---------------- fused gates 0+1: Z (bf16) and HR (bf16, in-place) -----------
// A: {xH(str256), px(128), xH+128(str256), pH(128)}; B: Z and R weight sets.
__launch_bounds__(256)
__global__ void mfma_gate01(const unsigned short* __restrict__ xH,
                            const unsigned short* __restrict__ px,
                            const unsigned short* __restrict__ pH,
                            const unsigned short* __restrict__ wt,
                            const float* __restrict__ bx, const float* __restrict__ bh,
                            unsigned short* __restrict__ zb,
                            unsigned short* __restrict__ xH_mut){
  const int M = 128*128;
  const unsigned short* Am[4] = {xH, px, xH + 128, pH};
  const int strA[4] = {256, 128, 256, 128};
  int lane = threadIdx.x & 63;
  int w    = threadIdx.x >> 6;
  int lr = lane & 15;
  int kb = (lane >> 4) * 8;
  int r0 = blockIdx.x * 128 + w * 32;

  f32x4 accZ[2][8], accR[2][8];
  #pragma unroll
  for (int i = 0; i < 2; ++i)
    #pragma unroll
    for (int c = 0; c < 8; ++c){
      accZ[i][c] = (f32x4){0.f,0.f,0.f,0.f};
      accR[i][c] = (f32x4){0.f,0.f,0.f,0.f};
    }

  int rA0 = min(r0 + lr,      N_NODES - 1);
  int rA1 = min(r0 + 16 + lr, N_NODES - 1);

  #pragma unroll
  for (int s = 0; s < 16; ++s){
    const int m = s >> 2;
    const int ko = (s & 3)*32 + kb;
    const unsigned short* Ap = Am[m] + ko;
    bf16x8 a0 = *(const bf16x8*)(Ap + (size_t)rA0*strA[m]);
    bf16x8 a1 = *(const bf16x8*)(Ap + (size_t)rA1*strA[m]);
    const unsigned short* Bz = wt + (size_t)(3*m + 0)*M + ko;
    const unsigned short* Br = wt + (size_t)(3*m + 1)*M + ko;
    #pragma unroll
    for (int c = 0; c < 8; ++c){
      bf16x8 bz = *(const bf16x8*)(Bz + (size_t)(c*16 + lr)*CH);
      bf16x8 br = *(const bf16x8*)(Br + (size_t)(c*16 + lr)*CH);
      accZ[0][c] = __builtin_amdgcn_mfma_f32_16x16x32_bf16(a0, bz, accZ[0][c], 0, 0, 0);
      accZ[1][c] = __builtin_amdgcn_mfma_f32_16x16x32_bf16(a1, bz, accZ[1][c], 0, 0, 0);
      accR[0][c] = __builtin_amdgcn_mfma_f32_16x16x32_bf16(a0, br, accR[0][c], 0, 0, 0);
      accR[1][c] = __builtin_amdgcn_mfma_f32_16x16x32_bf16(a1, br, accR[1][c], 0, 0, 0);
    }
  }

  float bsZ[8], bsR[8];
  #pragma unroll
  for (int c = 0; c < 8; ++c){
    bsZ[c] = bx[c*16 + lr]       + bh[c*16 + lr];
    bsR[c] = bx[128 + c*16 + lr] + bh[128 + c*16 + lr];
  }

  int rbase = r0 + (lane >> 4) * 4;
  #pragma unroll
  for (int i = 0; i < 2; ++i){
    #pragma unroll
    for (int j = 0; j < 4; ++j){
      int row = rbase + i*16 + j;
      if (row >= N_NODES) continue;
      size_t ro = (size_t)row * CH;
      size_t rh = (size_t)row * 256 + 128;
      #pragma unroll
      for (int c = 0; c < 8; ++c){
        int col = c*16 + lr;
        float z = 1.0f/(1.0f + __expf(-(accZ[i][c][j] + bsZ[c])));
        float r = 1.0f/(1.0f + __expf(-(accR[i][c][j] + bsR[c])));
        float h = bf2f(xH_mut[rh + col]);
        zb[ro + col]     = f2bf(z);
        xH_mut[rh + col] = f2bf(h * r);
      }
    }
  }
}

// ---------------- 2-matrix MFMA GEMM, epilogues: 2=raw fp32, 3=final GRU ------
template<int EPI>
__launch_bounds__(256)
__global__ void mfma_gemm2(const unsigned short* __restrict__ A0, int sA0,
                           const unsigned short* __restrict__ A1, int sA1,
                           const unsigned short* __restrict__ B0,
                           const unsigned short* __restrict__ B1,
                           const float* __restrict__ bias,
                           const float* __restrict__ Hp, const float* __restrict__ pre2,
                           const unsigned short* __restrict__ zb,
                           float* __restrict__ out0f,
                           unsigned short* __restrict__ out1b){
  const unsigned short* Am[2] = {A0, A1};
  const int strA[2] = {sA0, sA1};
  const unsigned short* Bm[2] = {B0, B1};
  int lane = threadIdx.x & 63;
  int w    = threadIdx.x >> 6;
  int lr = lane & 15;
  int kb = (lane >> 4) * 8;
  int r0 = blockIdx.x * 128 + w * 32;

  f32x4 acc[2][8];
  #pragma unroll
  for (int i = 0; i < 2; ++i)
    #pragma unroll
    for (int c = 0; c < 8; ++c) acc[i][c] = (f32x4){0.f,0.f,0.f,0.f};

  int rA0 = min(r0 + lr,      N_NODES - 1);
  int rA1 = min(r0 + 16 + lr, N_NODES - 1);

  #pragma unroll
  for (int s = 0; s < 8; ++s){
    const int m = s >> 2;
    const int ko = (s & 3)*32 + kb;
    const unsigned short* Ap = Am[m] + ko;
    bf16x8 a0 = *(const bf16x8*)(Ap + (size_t)rA0*strA[m]);
    bf16x8 a1 = *(const bf16x8*)(Ap + (size_t)rA1*strA[m]);
    const unsigned short* Bp = Bm[m] + ko;
    #pragma unroll
    for (int c = 0; c < 8; ++c){
      bf16x8 b = *(const bf16x8*)(Bp + (size_t)(c*16 + lr)*CH);
      acc[0][c] = __builtin_amdgcn_mfma_f32_16x16x32_bf16(a0, b, acc[0][c], 0, 0, 0);
      acc[1][c] = __builtin_amdgcn_mfma_f32_16x16x32_bf16(a1, b, acc[1][c], 0, 0, 0);
    }
  }

  float bs[8];
  #pragma unroll
  for (int c = 0; c < 8; ++c) bs[c] = bias[c*16 + lr];

  int rbase = r0 + (lane >> 4) * 4;
  #pragma unroll
  for (int i = 0; i < 2; ++i){
    #pragma unroll
    for (int j = 0; j < 4; ++j){
      int row = rbase + i*16 + j;
      if (row >= N_NODES) continue;
      size_t ro = (size_t)row * CH;
      #pragma unroll
      for (int c = 0; c < 8; ++c){
        int col = c*16 + lr;
        size_t o = ro + col;
        float v = acc[i][c][j] + bs[c];
        if (EPI == 2){
          out0f[o] = v;
        } else {
          float ht = tanhf(v + pre2[o]);
          float z  = bf2f(zb[o]);
          float h  = z*Hp[o] + (1.0f - z)*ht;
          out0f[o] = h;
          out1b[o] = f2bf(fmaxf(h, 0.0f));
        }
      }
    }
  }
}

// ---------------- link-pred scores: 16-lane group per pair, bf16 rows ---------
__global__ void scores_bf16(const int* __restrict__ eli, const unsigned short* __restrict__ hr,
                            const float* __restrict__ pw, const float* __restrict__ pb,
                            float* __restrict__ out){
  __shared__ float sw[CH];
  int t = threadIdx.x;
  if (t < CH) sw[t] = pw[2*t] + pw[2*t + 1];
  __syncthreads();
  int pair = blockIdx.x*16 + (t >> 4);
  if (pair >= N_EL) return;
  int il = t & 15;
  int a = eli[pair];
  int b = eli[N_EL + pair];
  bf16x8 va = *(const bf16x8*)(hr + (size_t)a*CH + il*8);
  bf16x8 vb = *(const bf16x8*)(hr + (size_t)b*CH + il*8);
  float s = 0.f;
  #pragma unroll
  for (int j = 0; j < 8; ++j){
    s += bf2f((unsigned short)va[j]) * bf2f((unsigned short)vb[j]) * sw[il*8 + j];
  }
  s += __shfl_xor(s, 1, 64);
  s += __shfl_xor(s, 2, 64);
  s += __shfl_xor(s, 4, 64);
  s += __shfl_xor(s, 8, 64);
  if (il == 0) out[pair] = s + pb[0] + pb[1];
}

extern "C" void kernel_launch(void* const* d_in, const int* in_sizes, int n_in,
                              void* d_out, int out_size, void* d_ws, size_t ws_size,
                              hipStream_t stream) {
  const float* x   = (const float*)d_in[0];
  const int*   ei  = (const int*)d_in[1];
  const int*   eli = (const int*)d_in[2];
  const float* H   = (const float*)d_in[3];
  const float* Wx0 = (const float*)d_in[4];
  const float* Wx1 = (const float*)d_in[5];
  const float* bx  = (const float*)d_in[6];
  const float* Wh0 = (const float*)d_in[7];
  const float* Wh1 = (const float*)d_in[8];
  const float* bh  = (const float*)d_in[9];
  const float* pw  = (const float*)d_in[10];
  const float* pb  = (const float*)d_in[11];
  float* out    = (float*)d_out;
  float* scores = out;
  float* hidden = out + N_EL;

  char* w = (char*)d_ws;
  auto alloc = [&](size_t b){ void* p = (void*)w; w += (b + 255) & ~(size_t)255; return p; };
  int*   deg      = (int*)  alloc((size_t)N_NODES*4);
  int*   cnt      = (int*)  alloc((size_t)N_NODES*4);
  float* dinv     = (float*)alloc((size_t)N_NODES*4);
  int*   rowoff   = (int*)  alloc((size_t)(N_NODES+1)*4);
  int*   cursor   = (int*)  alloc((size_t)N_NODES*4);
  int*   bsum     = (int*)  alloc((size_t)SCAN_NB*4);
  int*   boff     = (int*)  alloc((size_t)SCAN_NB*4);
  int*   csr_src  = (int*)  alloc((size_t)N_EDGES*4);
  float* csr_norm = (float*)alloc((size_t)N_EDGES*4);
  unsigned short* wt  = (unsigned short*)alloc((size_t)12*128*128*2);
  unsigned short* xHb = (unsigned short*)alloc((size_t)N_NODES*256*2);  // x|H interleaved
  unsigned short* pxb = (unsigned short*)alloc((size_t)N_NODES*CH*2);
  unsigned short* pHb = (unsigned short*)alloc((size_t)N_NODES*CH*2);
  unsigned short* zbb = (unsigned short*)alloc((size_t)N_NODES*CH*2);
  float* pre2 = (float*)alloc((size_t)N_NODES*CH*4);
  unsigned short* pHRb   = pHb;   // pHb dead after gate01
  unsigned short* relu_b = pxb;   // pxb dead after gate2x; final gemm doesn't read it

  hipMemsetAsync(deg, 0, (size_t)N_NODES*4, stream);
  hipMemsetAsync(cnt, 0, (size_t)N_NODES*4, stream);

  hist_kernel<<<(N_EDGES+255)/256, 256, 0, stream>>>(ei, deg, cnt);
  dinv_kernel<<<(N_NODES+255)/256, 256, 0, stream>>>(deg, dinv);
  scan_bsum <<<SCAN_NB, 256, 0, stream>>>(cnt, bsum);
  scan_boff <<<1, 256, 0, stream>>>(bsum, boff);
  scan_final<<<SCAN_NB, 256, 0, stream>>>(cnt, boff, rowoff, cursor);
  scatter_kernel<<<(N_EDGES+255)/256, 256, 0, stream>>>(ei, dinv, cursor, csr_src, csr_norm);

  cvt_xH<<<(((N_NODES*CH)/4)*2 + 255)/256, 256, 0, stream>>>(x, H, xHb);
  cvt_w <<<(12*128*128 + 255)/256, 256, 0, stream>>>(Wx0, Wx1, Wh0, Wh1, wt);

  prop_x2<<<(N_NODES+3)/4, 256, 0, stream>>>(rowoff, csr_src, csr_norm, xHb, pxb, pHb);

  const int GB = (N_NODES + 127) / 128;
  const int M = 128*128;
  // fused gates 0+1: Z (bf16) + HR (bf16, in-place into xHb H-half)
  mfma_gate01<<<GB, 256, 0, stream>>>(xHb, pxb, pHb, wt, bx, bh, zbb, xHb);
  // gate 2 x-part: pre2 = x@Wx0[2] + px@Wx1[2] + bx[2] (fp32)
  mfma_gemm2<2><<<GB, 256, 0, stream>>>(xHb, 256, pxb, 128,
      wt + (size_t)2*M, wt + (size_t)5*M, bx + 256,
      nullptr, nullptr, nullptr, pre2, nullptr);
  // pHR = prop(HR)  (HR lives in xHb H-half, stride 256)
  prop_one<<<(N_NODES+3)/4, 256, 0, stream>>>(rowoff, csr_src, csr_norm, xHb + 128, pHRb);
  // gate 2 h-part + GRU finalize: hidden (fp32, d_out) + relu (bf16)
  mfma_gemm2<3><<<GB, 256, 0, stream>>>(xHb + 128, 256, pHRb, 128,
      wt + (size_t)8*M, wt + (size_t)11*M, bh + 256,
      H, pre2, zbb, hidden, relu_b);

  scores_bf16<<<(N_EL+15)/16, 256, 0, stream>>>(eli, relu_b, pw, pb, scores);
}

// Round 5
// 444.743 us; speedup vs baseline: 2.0031x; 1.1561x over previous
//
#include <hip/hip_runtime.h>

#define N_NODES 50000
#define N_EDGES 800000
#define N_EL    200000
#define CH      128

typedef __attribute__((ext_vector_type(8))) short bf16x8;
typedef __attribute__((ext_vector_type(4))) float f32x4;

__device__ __forceinline__ unsigned short f2bf(float f){
  unsigned int u = __float_as_uint(f);
  unsigned int r = (u + 0x7fff + ((u >> 16) & 1)) >> 16;
  return (unsigned short)r;
}
__device__ __forceinline__ float bflo(unsigned int v){ return __uint_as_float(v << 16); }
__device__ __forceinline__ float bfhi(unsigned int v){ return __uint_as_float(v & 0xffff0000u); }
__device__ __forceinline__ float bf2f(unsigned short u){ return __uint_as_float(((unsigned int)u) << 16); }

__device__ __forceinline__ void gload16(const void* g, void* l){
  __builtin_amdgcn_global_load_lds(
      (const __attribute__((address_space(1))) unsigned int*)g,
      (__attribute__((address_space(3))) unsigned int*)l, 16, 0, 0);
}

// ---------------- degree histogram --------------------------------------------
__global__ void hist_kernel(const int* __restrict__ ei, int* deg, int* cnt){
  int i = blockIdx.x*blockDim.x + threadIdx.x;
  if (i < N_EDGES){
    atomicAdd(&deg[ei[i]], 1);
    atomicAdd(&cnt[ei[N_EDGES + i]], 1);
  }
}

__global__ void dinv_kernel(const int* __restrict__ deg, float* __restrict__ dinv){
  int i = blockIdx.x*blockDim.x + threadIdx.x;
  if (i < N_NODES){
    int d = deg[i];
    dinv[i] = d > 0 ? rsqrtf((float)d) : 0.0f;
  }
}

// ---------------- hierarchical exclusive scan ---------------------------------
#define SCAN_NB 196   // ceil(50000/256)

__global__ void scan_bsum(const int* __restrict__ cnt, int* __restrict__ bsum){
  __shared__ int sh[256];
  int i = blockIdx.x*256 + threadIdx.x;
  sh[threadIdx.x] = (i < N_NODES) ? cnt[i] : 0;
  __syncthreads();
  for (int off = 128; off >= 1; off >>= 1){
    if ((int)threadIdx.x < off) sh[threadIdx.x] += sh[threadIdx.x + off];
    __syncthreads();
  }
  if (threadIdx.x == 0) bsum[blockIdx.x] = sh[0];
}

__global__ void scan_boff(const int* __restrict__ bsum, int* __restrict__ boff){
  __shared__ int sh[256];
  int t = threadIdx.x;
  int v = (t < SCAN_NB) ? bsum[t] : 0;
  sh[t] = v;
  __syncthreads();
  for (int off = 1; off < 256; off <<= 1){
    int tv = (t >= off) ? sh[t - off] : 0;
    __syncthreads();
    sh[t] += tv;
    __syncthreads();
  }
  if (t < SCAN_NB) boff[t] = sh[t] - v;
}

__global__ void scan_final(const int* __restrict__ cnt, const int* __restrict__ boff,
                           int* __restrict__ rowoff, int* __restrict__ cursor){
  __shared__ int sh[256];
  int t = threadIdx.x;
  int i = blockIdx.x*256 + t;
  int v = (i < N_NODES) ? cnt[i] : 0;
  sh[t] = v;
  __syncthreads();
  for (int off = 1; off < 256; off <<= 1){
    int tv = (t >= off) ? sh[t - off] : 0;
    __syncthreads();
    sh[t] += tv;
    __syncthreads();
  }
  int o = boff[blockIdx.x] + sh[t] - v;
  if (i < N_NODES){ rowoff[i] = o; cursor[i] = o; }
  if (i == N_NODES - 1) rowoff[N_NODES] = N_EDGES;
}

__global__ void scatter_kernel(const int* __restrict__ ei, const float* __restrict__ dinv,
                               int* cursor, int* __restrict__ csr_src,
                               float* __restrict__ csr_norm){
  int i = blockIdx.x*blockDim.x + threadIdx.x;
  if (i < N_EDGES){
    int s = ei[i];
    int d = ei[N_EDGES + i];
    int pos = atomicAdd(&cursor[d], 1);
    csr_src[pos]  = s;
    csr_norm[pos] = -(dinv[s] * dinv[d]);
  }
}

// ---------------- converts ----------------------------------------------------
// xH[node][0..127]=bf16(x row), [128..255]=bf16(H row)
__global__ void cvt_xH(const float* __restrict__ x, const float* __restrict__ H,
                       unsigned short* __restrict__ xH){
  const int Q = (N_NODES*CH)/4;
  int i = blockIdx.x*blockDim.x + threadIdx.x;
  if (i >= 2*Q) return;
  const float* src = (i < Q) ? x : H;
  int off = (i < Q) ? i : i - Q;
  float4 v = ((const float4*)src)[off];
  int node = off >> 5, cg = off & 31;
  uint2 o;
  o.x = (unsigned int)f2bf(v.x) | ((unsigned int)f2bf(v.y) << 16);
  o.y = (unsigned int)f2bf(v.z) | ((unsigned int)f2bf(v.w) << 16);
  *(uint2*)(xH + (size_t)node*256 + ((i < Q) ? 0 : 128) + cg*4) = o;
}

// wt[m][col][k] = W_t[g][k][col], m = t*3+g, t in {Wx0,Wx1,Wh0,Wh1}
__global__ void cvt_w(const float* __restrict__ Wx0, const float* __restrict__ Wx1,
                      const float* __restrict__ Wh0, const float* __restrict__ Wh1,
                      unsigned short* __restrict__ wt){
  int i = blockIdx.x*blockDim.x + threadIdx.x;
  if (i >= 12*128*128) return;
  int m = i >> 14;
  int r = i & 16383;
  int col = r >> 7, k = r & 127;
  const float* W[4] = {Wx0, Wx1, Wh0, Wh1};
  const float* src = W[m/3] + (m%3)*16384;
  wt[i] = f2bf(src[k*128 + col]);
}

// ---------------- prop over interleaved x|H (one 512B read per edge) ----------
__global__ void prop_x2(const int* __restrict__ rowoff, const int* __restrict__ csr_src,
                        const float* __restrict__ csr_norm,
                        const unsigned short* __restrict__ xH,
                        unsigned short* __restrict__ px, unsigned short* __restrict__ pH){
  int node = blockIdx.x*4 + ((int)threadIdx.x >> 6);
  if (node >= N_NODES) return;
  int lane = threadIdx.x & 63;
  int half = lane >> 5, il = lane & 31;
  const unsigned short* base = xH + half*128 + il*4;
  int beg = rowoff[node], end = rowoff[node+1];
  float a0 = 0.f, a1 = 0.f, a2 = 0.f, a3 = 0.f;
  int k = beg;
  for (; k + 4 <= end; k += 4){
    int s0 = csr_src[k], s1 = csr_src[k+1], s2 = csr_src[k+2], s3 = csr_src[k+3];
    float w0 = csr_norm[k], w1 = csr_norm[k+1], w2 = csr_norm[k+2], w3 = csr_norm[k+3];
    uint2 v0 = *(const uint2*)(base + (size_t)s0*256);
    uint2 v1 = *(const uint2*)(base + (size_t)s1*256);
    uint2 v2 = *(const uint2*)(base + (size_t)s2*256);
    uint2 v3 = *(const uint2*)(base + (size_t)s3*256);
    a0 += w0*bflo(v0.x) + w1*bflo(v1.x) + w2*bflo(v2.x) + w3*bflo(v3.x);
    a1 += w0*bfhi(v0.x) + w1*bfhi(v1.x) + w2*bfhi(v2.x) + w3*bfhi(v3.x);
    a2 += w0*bflo(v0.y) + w1*bflo(v1.y) + w2*bflo(v2.y) + w3*bflo(v3.y);
    a3 += w0*bfhi(v0.y) + w1*bfhi(v1.y) + w2*bfhi(v2.y) + w3*bfhi(v3.y);
  }
  for (; k < end; ++k){
    int s = csr_src[k];
    float w = csr_norm[k];
    uint2 v = *(const uint2*)(base + (size_t)s*256);
    a0 += w*bflo(v.x); a1 += w*bfhi(v.x);
    a2 += w*bflo(v.y); a3 += w*bfhi(v.y);
  }
  uint2 o;
  o.x = (unsigned int)f2bf(a0) | ((unsigned int)f2bf(a1) << 16);
  o.y = (unsigned int)f2bf(a2) | ((unsigned int)f2bf(a3) << 16);
  unsigned short* O = (half ? pH : px) + (size_t)node*CH + il*4;
  *(uint2*)O = o;
}

// ---------------- prop of one matrix (stride-256 input) -----------------------
__global__ void prop_one(const int* __restrict__ rowoff, const int* __restrict__ csr_src,
                         const float* __restrict__ csr_norm,
                         const unsigned short* __restrict__ V, // stride 256
                         unsigned short* __restrict__ O){      // stride 128
  int node = blockIdx.x*4 + ((int)threadIdx.x >> 6);
  if (node >= N_NODES) return;
  int lane = threadIdx.x & 63;
  const unsigned short* base = V + lane*2;
  int beg = rowoff[node], end = rowoff[node+1];
  float a0 = 0.f, a1 = 0.f;
  int k = beg;
  for (; k + 4 <= end; k += 4){
    int s0 = csr_src[k], s1 = csr_src[k+1], s2 = csr_src[k+2], s3 = csr_src[k+3];
    float w0 = csr_norm[k], w1 = csr_norm[k+1], w2 = csr_norm[k+2], w3 = csr_norm[k+3];
    unsigned int v0 = *(const unsigned int*)(base + (size_t)s0*256);
    unsigned int v1 = *(const unsigned int*)(base + (size_t)s1*256);
    unsigned int v2 = *(const unsigned int*)(base + (size_t)s2*256);
    unsigned int v3 = *(const unsigned int*)(base + (size_t)s3*256);
    a0 += w0*bflo(v0) + w1*bflo(v1) + w2*bflo(v2) + w3*bflo(v3);
    a1 += w0*bfhi(v0) + w1*bfhi(v1) + w2*bfhi(v2) + w3*bfhi(v3);
  }
  for (; k < end; ++k){
    int s = csr_src[k];
    float w = csr_norm[k];
    unsigned int v = *(const unsigned int*)(base + (size_t)s*256);
    a0 += w*bflo(v); a1 += w*bfhi(v);
  }
  *(unsigned int*)(O + (size_t)node*CH + lane*2) =
      (unsigned int)f2bf(a0) | ((unsigned int)f2bf(a1) << 16);
}

// ---------------- fused gates Z, R, P2: LDS-staged B, 64 rows/block -----------
// waves: 4, each 16 rows. K: s=0..15 over {x,px,H,pH}; gate P2 only for s<8.
// B slice layout in LDS: [col][32k] with 16B-chunk XOR swizzle keyed on (col>>1)&3.
__launch_bounds__(256, 3)
__global__ void mfma_gates(unsigned short* xH,
                           const unsigned short* __restrict__ px,
                           const unsigned short* __restrict__ pH,
                           const unsigned short* __restrict__ wt,
                           const float* __restrict__ bx, const float* __restrict__ bh,
                           unsigned short* __restrict__ zb,
                           float* __restrict__ pre2){
  __shared__ unsigned short lds[2][3][4096];
  const int M = 128*128;
  int lane = threadIdx.x & 63;
  int w    = threadIdx.x >> 6;
  int lr   = lane & 15;
  int kq   = lane >> 4;                 // k-quarter 0..3
  int r0w  = blockIdx.x*64 + w*16;
  int rA   = min(r0w + lr, N_NODES - 1);

  const unsigned short* Am[4] = {xH, px, xH + 128, pH};
  const int strA[4] = {256, 128, 256, 128};

  // staging: per-lane global src carries the inverse swizzle; LDS dest linear
  const int scol = lane >> 2;                                   // col within 16-group
  const int skbe = (((lane & 3) ^ ((lane >> 3) & 3)) << 3);     // swz src elem off
  auto stage = [&](int s, int b){
    int t = s >> 2, ko = (s & 3) * 32;
    int nm = (t < 2) ? 3 : 2;
    for (int q = w; q < nm*8; q += 4){
      int g = q >> 3, i = q & 7;
      const unsigned short* src = wt + (size_t)(t*3 + g)*M
                                + (size_t)(i*16 + scol)*CH + ko + skbe;
      gload16(src, &lds[b][g][i*512]);
    }
  };

  f32x4 accZ[8], accR[8], accP[8];
  #pragma unroll
  for (int c = 0; c < 8; ++c){
    accZ[c] = (f32x4){0.f,0.f,0.f,0.f};
    accR[c] = (f32x4){0.f,0.f,0.f,0.f};
    accP[c] = (f32x4){0.f,0.f,0.f,0.f};
  }

  const int rdo = ((kq ^ ((lr >> 1) & 3)) << 3);   // swizzled read elem offset

  stage(0, 0);
  __syncthreads();
  #pragma unroll
  for (int s = 0; s < 16; ++s){
    const int b = s & 1;
    if (s < 15) stage(s + 1, b ^ 1);
    const int t = s >> 2, ko = (s & 3) * 32;
    bf16x8 a = *(const bf16x8*)(Am[t] + (size_t)rA*strA[t] + ko + kq*8);
    #pragma unroll
    for (int c = 0; c < 8; ++c){
      bf16x8 bz = *(const bf16x8*)&lds[b][0][(c*16 + lr)*32 + rdo];
      bf16x8 br = *(const bf16x8*)&lds[b][1][(c*16 + lr)*32 + rdo];
      accZ[c] = __builtin_amdgcn_mfma_f32_16x16x32_bf16(a, bz, accZ[c], 0, 0, 0);
      accR[c] = __builtin_amdgcn_mfma_f32_16x16x32_bf16(a, br, accR[c], 0, 0, 0);
      if (t < 2){
        bf16x8 bp = *(const bf16x8*)&lds[b][2][(c*16 + lr)*32 + rdo];
        accP[c] = __builtin_amdgcn_mfma_f32_16x16x32_bf16(a, bp, accP[c], 0, 0, 0);
      }
    }
    __syncthreads();
  }

  float bsZ[8], bsR[8], bsP[8];
  #pragma unroll
  for (int c = 0; c < 8; ++c){
    int col = c*16 + lr;
    bsZ[c] = bx[col]       + bh[col];
    bsR[c] = bx[128 + col] + bh[128 + col];
    bsP[c] = bx[256 + col];
  }

  #pragma unroll
  for (int j = 0; j < 4; ++j){
    int row = r0w + kq*4 + j;
    if (row >= N_NODES) continue;
    size_t ro = (size_t)row * CH;
    size_t rh = (size_t)row * 256 + 128;
    #pragma unroll
    for (int c = 0; c < 8; ++c){
      int col = c*16 + lr;
      float z = 1.0f/(1.0f + __expf(-(accZ[c][j] + bsZ[c])));
      float r = 1.0f/(1.0f + __expf(-(accR[c][j] + bsR[c])));
      float h = bf2f(xH[rh + col]);
      zb[ro + col]   = f2bf(z);
      xH[rh + col]   = f2bf(h * r);
      pre2[ro + col] = accP[c][j] + bsP[c];
    }
  }
}

// ---------------- final: gate2 h-part + GRU epilogue --------------------------
__launch_bounds__(256, 3)
__global__ void mfma_final(const unsigned short* __restrict__ hr,   // stride 256
                           const unsigned short* __restrict__ phr,  // stride 128
                           const unsigned short* __restrict__ B0,
                           const unsigned short* __restrict__ B1,
                           const float* __restrict__ bias,
                           const float* __restrict__ Hp, const float* __restrict__ pre2,
                           const unsigned short* __restrict__ zb,
                           float* __restrict__ hidden,
                           unsigned short* __restrict__ relu_b){
  __shared__ unsigned short lds[2][4096];
  int lane = threadIdx.x & 63;
  int w    = threadIdx.x >> 6;
  int lr   = lane & 15;
  int kq   = lane >> 4;
  int r0w  = blockIdx.x*64 + w*16;
  int rA   = min(r0w + lr, N_NODES - 1);

  const unsigned short* Am[2] = {hr, phr};
  const int strA[2] = {256, 128};

  const int scol = lane >> 2;
  const int skbe = (((lane & 3) ^ ((lane >> 3) & 3)) << 3);
  auto stage = [&](int s, int b){
    int t = s >> 2, ko = (s & 3) * 32;
    const unsigned short* B = t ? B1 : B0;
    for (int q = w; q < 8; q += 4){
      const unsigned short* src = B + (size_t)(q*16 + scol)*CH + ko + skbe;
      gload16(src, &lds[b][q*512]);
    }
  };

  f32x4 acc[8];
  #pragma unroll
  for (int c = 0; c < 8; ++c) acc[c] = (f32x4){0.f,0.f,0.f,0.f};

  const int rdo = ((kq ^ ((lr >> 1) & 3)) << 3);

  stage(0, 0);
  __syncthreads();
  #pragma unroll
  for (int s = 0; s < 8; ++s){
    const int b = s & 1;
    if (s < 7) stage(s + 1, b ^ 1);
    const int t = s >> 2, ko = (s & 3) * 32;
    bf16x8 a = *(const bf16x8*)(Am[t] + (size_t)rA*strA[t] + ko + kq*8);
    #pragma unroll
    for (int c = 0; c < 8; ++c){
      bf16x8 bb = *(const bf16x8*)&lds[b][(c*16 + lr)*32 + rdo];
      acc[c] = __builtin_amdgcn_mfma_f32_16x16x32_bf16(a, bb, acc[c], 0, 0, 0);
    }
    __syncthreads();
  }

  float bs[8];
  #pragma unroll
  for (int c = 0; c < 8; ++c) bs[c] = bias[c*16 + lr];

  #pragma unroll
  for (int j = 0; j < 4; ++j){
    int row = r0w + kq*4 + j;
    if (row >= N_NODES) continue;
    size_t ro = (size_t)row * CH;
    #pragma unroll
    for (int c = 0; c < 8; ++c){
      size_t o = ro + c*16 + lr;
      float ht = tanhf(acc[c][j] + bs[c] + pre2[o]);
      float z  = bf2f(zb[o]);
      float h  = z*Hp[o] + (1.0f - z)*ht;
      hidden[o] = h;
      relu_b[o] = f2bf(fmaxf(h, 0.0f));
    }
  }
}

// ---------------- link-pred scores: 16-lane group per pair, bf16 rows ---------
__global__ void scores_bf16(const int* __restrict__ eli, const unsigned short* __restrict__ hr,
                            const float* __restrict__ pw, const float* __restrict__ pb,
                            float* __restrict__ out){
  __shared__ float sw[CH];
  int t = threadIdx.x;
  if (t < CH) sw[t] = pw[2*t] + pw[2*t + 1];
  __syncthreads();
  int pair = blockIdx.x*16 + (t >> 4);
  if (pair >= N_EL) return;
  int il = t & 15;
  int a = eli[pair];
  int b = eli[N_EL + pair];
  bf16x8 va = *(const bf16x8*)(hr + (size_t)a*CH + il*8);
  bf16x8 vb = *(const bf16x8*)(hr + (size_t)b*CH + il*8);
  float s = 0.f;
  #pragma unroll
  for (int j = 0; j < 8; ++j){
    s += bf2f((unsigned short)va[j]) * bf2f((unsigned short)vb[j]) * sw[il*8 + j];
  }
  s += __shfl_xor(s, 1, 64);
  s += __shfl_xor(s, 2, 64);
  s += __shfl_xor(s, 4, 64);
  s += __shfl_xor(s, 8, 64);
  if (il == 0) out[pair] = s + pb[0] + pb[1];
}

extern "C" void kernel_launch(void* const* d_in, const int* in_sizes, int n_in,
                              void* d_out, int out_size, void* d_ws, size_t ws_size,
                              hipStream_t stream) {
  const float* x   = (const float*)d_in[0];
  const int*   ei  = (const int*)d_in[1];
  const int*   eli = (const int*)d_in[2];
  const float* H   = (const float*)d_in[3];
  const float* Wx0 = (const float*)d_in[4];
  const float* Wx1 = (const float*)d_in[5];
  const float* bx  = (const float*)d_in[6];
  const float* Wh0 = (const float*)d_in[7];
  const float* Wh1 = (const float*)d_in[8];
  const float* bh  = (const float*)d_in[9];
  const float* pw  = (const float*)d_in[10];
  const float* pb  = (const float*)d_in[11];
  float* out    = (float*)d_out;
  float* scores = out;
  float* hidden = out + N_EL;

  char* w = (char*)d_ws;
  auto alloc = [&](size_t b){ void* p = (void*)w; w += (b + 255) & ~(size_t)255; return p; };
  int*   deg      = (int*)  alloc((size_t)N_NODES*4);
  int*   cnt      = (int*)  alloc((size_t)N_NODES*4);
  float* dinv     = (float*)alloc((size_t)N_NODES*4);
  int*   rowoff   = (int*)  alloc((size_t)(N_NODES+1)*4);
  int*   cursor   = (int*)  alloc((size_t)N_NODES*4);
  int*   bsum     = (int*)  alloc((size_t)SCAN_NB*4);
  int*   boff     = (int*)  alloc((size_t)SCAN_NB*4);
  int*   csr_src  = (int*)  alloc((size_t)N_EDGES*4);
  float* csr_norm = (float*)alloc((size_t)N_EDGES*4);
  unsigned short* wt  = (unsigned short*)alloc((size_t)12*128*128*2);
  unsigned short* xHb = (unsigned short*)alloc((size_t)N_NODES*256*2);  // x|H interleaved
  unsigned short* pxb = (unsigned short*)alloc((size_t)N_NODES*CH*2);
  unsigned short* pHb = (unsigned short*)alloc((size_t)N_NODES*CH*2);
  unsigned short* zbb = (unsigned short*)alloc((size_t)N_NODES*CH*2);
  float* pre2 = (float*)alloc((size_t)N_NODES*CH*4);
  unsigned short* pHRb   = pHb;   // pHb dead after mfma_gates
  unsigned short* relu_b = pxb;   // pxb dead after mfma_gates

  hipMemsetAsync(deg, 0, (size_t)N_NODES*4, stream);
  hipMemsetAsync(cnt, 0, (size_t)N_NODES*4, stream);

  hist_kernel<<<(N_EDGES+255)/256, 256, 0, stream>>>(ei, deg, cnt);
  dinv_kernel<<<(N_NODES+255)/256, 256, 0, stream>>>(deg, dinv);
  scan_bsum <<<SCAN_NB, 256, 0, stream>>>(cnt, bsum);
  scan_boff <<<1, 256, 0, stream>>>(bsum, boff);
  scan_final<<<SCAN_NB, 256, 0, stream>>>(cnt, boff, rowoff, cursor);
  scatter_kernel<<<(N_EDGES+255)/256, 256, 0, stream>>>(ei, dinv, cursor, csr_src, csr_norm);

  cvt_xH<<<(((N_NODES*CH)/4)*2 + 255)/256, 256, 0, stream>>>(x, H, xHb);
  cvt_w <<<(12*128*128 + 255)/256, 256, 0, stream>>>(Wx0, Wx1, Wh0, Wh1, wt);

  prop_x2<<<(N_NODES+3)/4, 256, 0, stream>>>(rowoff, csr_src, csr_norm, xHb, pxb, pHb);

  const int GB = (N_NODES + 63) / 64;   // 782 blocks
  const size_t M = 128*128;
  // fused gates: Z (bf16) + HR (bf16 in-place into xHb H-half) + pre2 (fp32)
  mfma_gates<<<GB, 256, 0, stream>>>(xHb, pxb, pHb, wt, bx, bh, zbb, pre2);
  // pHR = prop(HR)
  prop_one<<<(N_NODES+3)/4, 256, 0, stream>>>(rowoff, csr_src, csr_norm, xHb + 128, pHRb);
  // gate 2 h-part + GRU finalize: hidden (fp32, d_out) + relu (bf16)
  mfma_final<<<GB, 256, 0, stream>>>(xHb + 128, pHRb, wt + 8*M, wt + 11*M,
      bh + 256, H, pre2, zbb, hidden, relu_b);

  scores_bf16<<<(N_EL+15)/16, 256, 0, stream>>>(eli, relu_b, pw, pb, scores);
}